// Round 2
// baseline (240.054 us; speedup 1.0000x reference)
//
#include <hip/hip_runtime.h>
#include <hip/hip_bf16.h>
#include <math.h>

#define DIM 512
#define NH 8
#define HD 64
#define TT 1024
#define CH 16      // chunks per (b,h) sequence
#define CL 64      // chunk length (CH*CL == TT)
#define EPSF 1e-5f

// online logsumexp update: state (M,S) represents sum = S * exp(M)
__device__ __forceinline__ void lse_update(float &M, float &S, float e) {
    float nm = fmaxf(M, e);
    S = fmaf(S, __expf(M - nm), __expf(e - nm));
    M = nm;
}

// ---------------- Kernel 1: fused QKV projection + activations ----------------
// grid: (NH colTiles, rowTiles, 3)  block: 256
__launch_bounds__(256)
__global__ void k_gemm_qkv(const float* __restrict__ x,
                           const float* __restrict__ wq, const float* __restrict__ bq,
                           const float* __restrict__ wk, const float* __restrict__ bk,
                           const float* __restrict__ wv, const float* __restrict__ bv,
                           const float* __restrict__ lbeta, const float* __restrict__ ltemp,
                           float* __restrict__ Qf, float* __restrict__ Kf, float* __restrict__ Vv)
{
    const int z = blockIdx.z;
    const float* __restrict__ w    = (z == 0) ? wq : (z == 1) ? wk : wv;
    const float* __restrict__ bias = (z == 0) ? bq : (z == 1) ? bk : bv;
    const int h = blockIdx.x;
    const int rowBase = blockIdx.y * 64;
    const int colBase = h * 64;

    __shared__ __align__(16) float As[16][68];
    __shared__ __align__(16) float Bs[16][64];

    const int tid = threadIdx.x;
    const int ty = tid >> 4, tx = tid & 15;
    const int r0 = ty * 4, c0 = tx * 4;
    const int ar = tid >> 2, ak = (tid & 3) * 4;
    const int bkr = tid >> 4, bc = (tid & 15) * 4;

    float acc[4][4] = {};

    for (int k0 = 0; k0 < DIM; k0 += 16) {
        float4 av = *(const float4*)&x[(size_t)(rowBase + ar) * DIM + k0 + ak];
        As[ak + 0][ar] = av.x; As[ak + 1][ar] = av.y;
        As[ak + 2][ar] = av.z; As[ak + 3][ar] = av.w;
        *(float4*)&Bs[bkr][bc] = *(const float4*)&w[(size_t)(k0 + bkr) * DIM + colBase + bc];
        __syncthreads();
#pragma unroll
        for (int kk = 0; kk < 16; kk++) {
            float4 a = *(const float4*)&As[kk][r0];
            float4 b = *(const float4*)&Bs[kk][c0];
            float aa[4] = {a.x, a.y, a.z, a.w};
            float bb[4] = {b.x, b.y, b.z, b.w};
#pragma unroll
            for (int i = 0; i < 4; i++)
#pragma unroll
                for (int j = 0; j < 4; j++)
                    acc[i][j] = fmaf(aa[i], bb[j], acc[i][j]);
        }
        __syncthreads();
    }

    float b4[4] = { bias[colBase + c0 + 0], bias[colBase + c0 + 1],
                    bias[colBase + c0 + 2], bias[colBase + c0 + 3] };

    if (z == 2) {
#pragma unroll
        for (int i = 0; i < 4; i++) {
            int rr = rowBase + r0 + i;
            int bbn = rr >> 10, t = rr & (TT - 1);
            float4 o;
            o.x = acc[i][0] + b4[0]; o.y = acc[i][1] + b4[1];
            o.z = acc[i][2] + b4[2]; o.w = acc[i][3] + b4[3];
            *(float4*)&Vv[(((size_t)(bbn * NH + h)) * TT + t) * HD + c0] = o;
        }
    } else {
        float beta = expf(lbeta[h]);
        float invb = 1.0f / beta;
        float itemp = 1.0f / expf(ltemp[h]);
        float* __restrict__ dst = (z == 0) ? Qf : Kf;
#pragma unroll
        for (int i = 0; i < 4; i++) {
            int rr = rowBase + r0 + i;
            int bbn = rr >> 10, t = rr & (TT - 1);
            float v4[4];
#pragma unroll
            for (int j = 0; j < 4; j++) {
                float val = (acc[i][j] + b4[j]) * itemp;
                float zz = beta * val;
                v4[j] = (fmaxf(zz, 0.f) + log1pf(expf(-fabsf(zz)))) * invb;
            }
            float4 o = { v4[0], v4[1], v4[2], v4[3] };
            *(float4*)&dst[(((size_t)(bbn * NH + h)) * TT + t) * HD + c0] = o;
        }
    }
}

// ---------------- Kernel 2: per-chunk local reduction ----------------
// grid: (CH*2, NH, B)  block: 256. q-split: block handles 32 of 64 q's.
// thread: q = qh*32 + (tid&31), p-group g = tid>>5 owns p in [8g, 8g+8)
__launch_bounds__(256)
__global__ void k_chunk_reduce(const float* __restrict__ Kf, const float* __restrict__ Vv,
                               float* __restrict__ aAM, float* __restrict__ aAS,
                               float* __restrict__ aDM, float* __restrict__ aDS,
                               float* __restrict__ aCM)
{
    const int c = blockIdx.x >> 1, qh = blockIdx.x & 1;
    const int bh = blockIdx.z * NH + blockIdx.y;
    const int tid = threadIdx.x;

    __shared__ __align__(16) float sK[CL * HD];
    __shared__ __align__(16) float sV[CL * HD];
    __shared__ __align__(16) float sM0[CL * HD];

    size_t base = ((size_t)bh * TT + (size_t)c * CL) * HD;
    const float4* K4 = (const float4*)(Kf + base);
    const float4* V4 = (const float4*)(Vv + base);
#pragma unroll
    for (int r = 0; r < 4; r++) {
        int f = tid + 256 * r;
        float4 kv = K4[f];
        ((float4*)sK)[f] = kv;
        float4 m;
        m.x = __logf(kv.x + EPSF); m.y = __logf(kv.y + EPSF);
        m.z = __logf(kv.z + EPSF); m.w = __logf(kv.w + EPSF);
        ((float4*)sM0)[f] = m;
        ((float4*)sV)[f] = V4[f];
    }
    __syncthreads();

    const int q = qh * 32 + (tid & 31);
    const int g = tid >> 5, p0 = g * 8;
    float M[8], S[8];
#pragma unroll
    for (int j = 0; j < 8; j++) { M[j] = -INFINITY; S[j] = 0.f; }
    float MD = -INFINITY, SD = 0.f, cmx = 0.f;
    const bool doD = (qh == 0) && (tid < 64);

    for (int s = 0; s < CL; s++) {
        float kq = sK[s * HD + q];
#pragma unroll
        for (int j4 = 0; j4 < 2; j4++) {
            float4 vv = *(const float4*)&sV[s * HD + p0 + j4 * 4];
            float4 mm = *(const float4*)&sM0[s * HD + p0 + j4 * 4];
            lse_update(M[j4 * 4 + 0], S[j4 * 4 + 0], fmaf(vv.x, kq, mm.x));
            lse_update(M[j4 * 4 + 1], S[j4 * 4 + 1], fmaf(vv.y, kq, mm.y));
            lse_update(M[j4 * 4 + 2], S[j4 * 4 + 2], fmaf(vv.z, kq, mm.z));
            lse_update(M[j4 * 4 + 3], S[j4 * 4 + 3], fmaf(vv.w, kq, mm.w));
        }
        if (doD) {
            float kn = sK[s * HD + tid];
            float m0n = sM0[s * HD + tid];
            lse_update(MD, SD, kn + m0n);
            cmx = fmaxf(cmx, kn + EPSF);
        }
    }

    size_t abase = ((size_t)bh * CH + c) * 4096;
#pragma unroll
    for (int j = 0; j < 8; j++) {
        aAM[abase + (size_t)(p0 + j) * HD + q] = M[j];
        aAS[abase + (size_t)(p0 + j) * HD + q] = S[j];
    }
    if (doD) {
        size_t dbase = ((size_t)bh * CH + c) * HD + tid;
        aDM[dbase] = MD; aDS[dbase] = SD; aCM[dbase] = cmx;
    }
}

// ---------------- Kernel 3: exclusive scan of chunk aggregates ----------------
__global__ void k_scan_agg(float* __restrict__ aAM, float* __restrict__ aAS,
                           float* __restrict__ aDM, float* __restrict__ aDS,
                           float* __restrict__ aCM, int BH)
{
    int idx = blockIdx.x * 256 + threadIdx.x;
    int nA = BH * 4096, nD = BH * 64;
    if (idx < nA) {
        int bh = idx >> 12, pn = idx & 4095;
        float Mr = -INFINITY, Sr = 0.f;
        for (int c = 0; c < CH; c++) {
            size_t off = ((size_t)bh * CH + c) * 4096 + pn;
            float Mc = aAM[off], Sc = aAS[off];
            aAM[off] = Mr; aAS[off] = Sr;
            float nm = fmaxf(Mr, Mc);
            Sr = fmaf(Sr, __expf(Mr - nm), Sc * __expf(Mc - nm));
            Mr = nm;
        }
    } else if (idx < nA + nD) {
        int i = idx - nA; int bh = i >> 6, n = i & 63;
        float Mr = -INFINITY, Sr = 0.f;
        for (int c = 0; c < CH; c++) {
            size_t off = ((size_t)bh * CH + c) * HD + n;
            float Mc = aDM[off], Sc = aDS[off];
            aDM[off] = Mr; aDS[off] = Sr;
            float nm = fmaxf(Mr, Mc);
            Sr = fmaf(Sr, __expf(Mr - nm), Sc * __expf(Mc - nm));
            Mr = nm;
        }
    } else if (idx < nA + 2 * nD) {
        int i = idx - nA - nD; int bh = i >> 6, n = i & 63;
        float r = 0.f;
        for (int c = 0; c < CH; c++) {
            size_t off = ((size_t)bh * CH + c) * HD + n;
            float v = aCM[off];
            aCM[off] = r;
            r = fmaxf(r, v);
        }
    }
}

// ---------------- Kernel 4: within-chunk rescan + output Y ----------------
// grid: (CH*2, NH, B)  block: 256 (4 waves). q-split: block handles 32 q's.
// Wave w handles 8 q's: lane = g*8 + qil, g=p-group of 8, qi = w*8+qil.
// Barrier-free after staging: Σ_p via 3 shfl_xor; every wave redundantly
// maintains the per-p D-scan (lane owns p=lane) for the t1/t2 reductions.
__launch_bounds__(256)
__global__ void k_chunk_out(const float* __restrict__ Kf, const float* __restrict__ Vv,
                            const float* __restrict__ Qf,
                            const float* __restrict__ aAM, const float* __restrict__ aAS,
                            const float* __restrict__ aDM, const float* __restrict__ aDS,
                            const float* __restrict__ aCM,
                            const float* __restrict__ lsharp, float* __restrict__ Ym)
{
    const int c = blockIdx.x >> 1, qh = blockIdx.x & 1;
    const int hh = blockIdx.y, bb = blockIdx.z;
    const int bh = bb * NH + hh;
    const int tid = threadIdx.x;

    __shared__ __align__(16) float sK[CL * HD];
    __shared__ __align__(16) float sV[CL * HD];
    __shared__ __align__(16) float sM0[CL * HD];
    __shared__ __align__(16) float sQ[CL * HD];

    size_t base = ((size_t)bh * TT + (size_t)c * CL) * HD;
    const float4* K4 = (const float4*)(Kf + base);
    const float4* V4 = (const float4*)(Vv + base);
    const float4* Q4 = (const float4*)(Qf + base);
#pragma unroll
    for (int r = 0; r < 4; r++) {
        int f = tid + 256 * r;
        float4 kv = K4[f];
        ((float4*)sK)[f] = kv;
        float4 m;
        m.x = __logf(kv.x + EPSF); m.y = __logf(kv.y + EPSF);
        m.z = __logf(kv.z + EPSF); m.w = __logf(kv.w + EPSF);
        ((float4*)sM0)[f] = m;
        ((float4*)sV)[f] = V4[f];
        ((float4*)sQ)[f] = Q4[f];
    }
    __syncthreads();

    const int lane = tid & 63, w = tid >> 6;
    const int g = lane >> 3, qil = lane & 7;
    const int q = qh * 32 + w * 8 + qil;
    const int p0 = g * 8;

    float M[8], S[8];
    size_t abase = ((size_t)bh * CH + c) * 4096;
#pragma unroll
    for (int j = 0; j < 8; j++) {
        M[j] = aAM[abase + (size_t)(p0 + j) * HD + q];
        S[j] = aAS[abase + (size_t)(p0 + j) * HD + q];
    }
    // D-state: lane owns p = lane (redundant per wave, cheap)
    size_t dbase = ((size_t)bh * CH + c) * HD + lane;
    float MD = aDM[dbase], SD = aDS[dbase], cmx = aCM[dbase];

    const float sharp = expf(lsharp[hh]);
    const float invT = 1.0f / (float)TT;

    for (int s = 0; s < CL; s++) {
        float kq = sK[s * HD + q];
        float part = 0.f;
#pragma unroll
        for (int j4 = 0; j4 < 2; j4++) {
            float4 vv = *(const float4*)&sV[s * HD + p0 + j4 * 4];
            float4 mm = *(const float4*)&sM0[s * HD + p0 + j4 * 4];
            float4 qv = *(const float4*)&sQ[s * HD + p0 + j4 * 4];
#define STEPJ(compo, jj) { \
            lse_update(M[jj], S[jj], fmaf(vv.compo, kq, mm.compo)); \
            part = fmaf(qv.compo, M[jj] + __logf(S[jj]), part); }
            STEPJ(x, j4 * 4 + 0)
            STEPJ(y, j4 * 4 + 1)
            STEPJ(z, j4 * 4 + 2)
            STEPJ(w, j4 * 4 + 3)
#undef STEPJ
        }
        // reduce part over the 8 p-groups (lanes differing in bits 3..5)
        part += __shfl_xor(part, 8);
        part += __shfl_xor(part, 16);
        part += __shfl_xor(part, 32);

        // per-p denominator scan (lane owns p = lane)
        float kn = sK[s * HD + lane];
        float m0n = sM0[s * HD + lane];
        lse_update(MD, SD, kn + m0n);
        cmx = fmaxf(cmx, kn + EPSF);
        float qn = sQ[s * HD + lane];
        float t1 = qn * __logf(cmx);
        float t2 = qn * (MD + __logf(SD));
#pragma unroll
        for (int off = 1; off <= 32; off <<= 1) {
            t1 += __shfl_xor(t1, off);
            t2 += __shfl_xor(t2, off);
        }

        float num = part - t1;
        float den = t2 - t1 + EPSF;
        float yv = num / den;
        float ay = __powf(fabsf(yv), sharp);
        int tg = c * CL + s;
        float outv = copysignf(ay, yv) * ((float)(tg + 1) * invT);
        if (g == 0)
            Ym[((size_t)(bb * TT + tg)) * DIM + hh * HD + q] = outv;
    }
}

// ---------------- Kernel 5: output projection ----------------
__launch_bounds__(256)
__global__ void k_gemm_out(const float* __restrict__ A, const float* __restrict__ w,
                           const float* __restrict__ bias, float* __restrict__ out)
{
    const int rowBase = blockIdx.y * 64;
    const int colBase = blockIdx.x * 64;
    __shared__ __align__(16) float As[16][68];
    __shared__ __align__(16) float Bs[16][64];
    const int tid = threadIdx.x;
    const int ty = tid >> 4, tx = tid & 15;
    const int r0 = ty * 4, c0 = tx * 4;
    const int ar = tid >> 2, ak = (tid & 3) * 4;
    const int bkr = tid >> 4, bc = (tid & 15) * 4;

    float acc[4][4] = {};
    for (int k0 = 0; k0 < DIM; k0 += 16) {
        float4 av = *(const float4*)&A[(size_t)(rowBase + ar) * DIM + k0 + ak];
        As[ak + 0][ar] = av.x; As[ak + 1][ar] = av.y;
        As[ak + 2][ar] = av.z; As[ak + 3][ar] = av.w;
        *(float4*)&Bs[bkr][bc] = *(const float4*)&w[(size_t)(k0 + bkr) * DIM + colBase + bc];
        __syncthreads();
#pragma unroll
        for (int kk = 0; kk < 16; kk++) {
            float4 a = *(const float4*)&As[kk][r0];
            float4 b = *(const float4*)&Bs[kk][c0];
            float aa[4] = {a.x, a.y, a.z, a.w};
            float bb[4] = {b.x, b.y, b.z, b.w};
#pragma unroll
            for (int i = 0; i < 4; i++)
#pragma unroll
                for (int j = 0; j < 4; j++)
                    acc[i][j] = fmaf(aa[i], bb[j], acc[i][j]);
        }
        __syncthreads();
    }
    float b4[4] = { bias[colBase + c0 + 0], bias[colBase + c0 + 1],
                    bias[colBase + c0 + 2], bias[colBase + c0 + 3] };
#pragma unroll
    for (int i = 0; i < 4; i++) {
        int rr = rowBase + r0 + i;
        float4 o;
        o.x = acc[i][0] + b4[0]; o.y = acc[i][1] + b4[1];
        o.z = acc[i][2] + b4[2]; o.w = acc[i][3] + b4[3];
        *(float4*)&out[(size_t)rr * DIM + colBase + c0] = o;
    }
}

extern "C" void kernel_launch(void* const* d_in, const int* in_sizes, int n_in,
                              void* d_out, int out_size, void* d_ws, size_t ws_size,
                              hipStream_t stream)
{
    const float* x  = (const float*)d_in[0];
    const float* wq = (const float*)d_in[1];
    const float* bq = (const float*)d_in[2];
    const float* wk = (const float*)d_in[3];
    const float* bk = (const float*)d_in[4];
    const float* wv = (const float*)d_in[5];
    const float* bv = (const float*)d_in[6];
    const float* wo = (const float*)d_in[7];
    const float* bo = (const float*)d_in[8];
    const float* lb = (const float*)d_in[9];
    const float* lt = (const float*)d_in[10];
    const float* ls = (const float*)d_in[11];

    const int B  = in_sizes[0] / (TT * DIM);   // 2
    const int BH = B * NH;                     // 16

    float* ws  = (float*)d_ws;
    float* Qf  = ws;
    float* Kf  = Qf  + (size_t)BH * TT * HD;
    float* Vv  = Kf  + (size_t)BH * TT * HD;
    float* Ym  = Vv  + (size_t)BH * TT * HD;
    float* aAM = Ym  + (size_t)B * TT * DIM;
    float* aAS = aAM + (size_t)BH * CH * 4096;
    float* aDM = aAS + (size_t)BH * CH * 4096;
    float* aDS = aDM + (size_t)BH * CH * HD;
    float* aCM = aDS + (size_t)BH * CH * HD;

    dim3 g1(NH, (B * TT) / 64, 3);
    k_gemm_qkv<<<g1, 256, 0, stream>>>(x, wq, bq, wk, bk, wv, bv, lb, lt, Qf, Kf, Vv);

    dim3 g2(CH * 2, NH, B);
    k_chunk_reduce<<<g2, 256, 0, stream>>>(Kf, Vv, aAM, aAS, aDM, aDS, aCM);

    int ntot = BH * 4096 + 2 * BH * 64;
    k_scan_agg<<<(ntot + 255) / 256, 256, 0, stream>>>(aAM, aAS, aDM, aDS, aCM, BH);

    k_chunk_out<<<g2, 256, 0, stream>>>(Kf, Vv, Qf, aAM, aAS, aDM, aDS, aCM, ls, Ym);

    dim3 g5(NH, (B * TT) / 64, 1);
    k_gemm_out<<<g5, 256, 0, stream>>>(Ym, wo, bo, (float*)d_out);
}

// Round 4
// 149.440 us; speedup vs baseline: 1.6064x; 1.6064x over previous
//
#include <hip/hip_runtime.h>
#include <hip/hip_bf16.h>
#include <math.h>

#define DIM 512
#define NH 8
#define HD 64
#define TT 1024
#define CH 32      // chunks per (b,h) sequence
#define CL 32      // chunk length (CH*CL == TT)
#define EPSF 1e-5f
#define LN2F 0.69314718056f
#define LOG2EF 1.44269504089f

// raw gfx950 hardware transcendentals: v_exp_f32 = 2^x, v_log_f32 = log2(x)
__device__ __forceinline__ float fexp2(float x) { return __builtin_amdgcn_exp2f(x); }
__device__ __forceinline__ float flog2(float x) { return __builtin_amdgcn_logf(x); }

// Linear-space scan reformulation:
//   A[t,p,n]  = sum_{s<=t} exp(v[s,p]*Kf[s,n] + m0[s,p]),  m0 = ln(Kf+eps)
//   A_D[t,n]  = sum_{s<=t} exp(Kf[s,n] + m0[s,n])
//   m_c[t,p]  = ln(cummax(Kf+eps))
//   num[t,q]  = sum_p Qf[t,p]*ln A[t,p,q] - c1,   c1 = sum_p Qf*m_c
//   den[t]    = sum_p Qf[t,p]*(ln A_D - m_c) + eps
// All exponentials/logs done base-2 with scales folded into staged arrays:
//   Vv2 = v*log2e, Qf2 = Qf*ln2, m02 = log2(Kf+eps).
// f32 range check: max exponent ~2^83, sums < 1e28 -- safe.

// ---------------- Kernel 1: fused QKV projection + activations ----------------
__launch_bounds__(256)
__global__ void k_gemm_qkv(const float* __restrict__ x,
                           const float* __restrict__ wq, const float* __restrict__ bq,
                           const float* __restrict__ wk, const float* __restrict__ bk,
                           const float* __restrict__ wv, const float* __restrict__ bv,
                           const float* __restrict__ lbeta, const float* __restrict__ ltemp,
                           float* __restrict__ Qf2, float* __restrict__ Kf, float* __restrict__ Vv2)
{
    const int z = blockIdx.z;
    const float* __restrict__ w    = (z == 0) ? wq : (z == 1) ? wk : wv;
    const float* __restrict__ bias = (z == 0) ? bq : (z == 1) ? bk : bv;
    const int h = blockIdx.x;
    const int rowBase = blockIdx.y * 64;
    const int colBase = h * 64;

    __shared__ __align__(16) float As[16][68];
    __shared__ __align__(16) float Bs[16][64];

    const int tid = threadIdx.x;
    const int ty = tid >> 4, tx = tid & 15;
    const int r0 = ty * 4, c0 = tx * 4;
    const int ar = tid >> 2, ak = (tid & 3) * 4;
    const int bkr = tid >> 4, bc = (tid & 15) * 4;

    float acc[4][4] = {};

    for (int k0 = 0; k0 < DIM; k0 += 16) {
        float4 av = *(const float4*)&x[(size_t)(rowBase + ar) * DIM + k0 + ak];
        As[ak + 0][ar] = av.x; As[ak + 1][ar] = av.y;
        As[ak + 2][ar] = av.z; As[ak + 3][ar] = av.w;
        *(float4*)&Bs[bkr][bc] = *(const float4*)&w[(size_t)(k0 + bkr) * DIM + colBase + bc];
        __syncthreads();
#pragma unroll
        for (int kk = 0; kk < 16; kk++) {
            float4 a = *(const float4*)&As[kk][r0];
            float4 b = *(const float4*)&Bs[kk][c0];
            float aa[4] = {a.x, a.y, a.z, a.w};
            float bb[4] = {b.x, b.y, b.z, b.w};
#pragma unroll
            for (int i = 0; i < 4; i++)
#pragma unroll
                for (int j = 0; j < 4; j++)
                    acc[i][j] = fmaf(aa[i], bb[j], acc[i][j]);
        }
        __syncthreads();
    }

    float b4[4] = { bias[colBase + c0 + 0], bias[colBase + c0 + 1],
                    bias[colBase + c0 + 2], bias[colBase + c0 + 3] };

    if (z == 2) {
#pragma unroll
        for (int i = 0; i < 4; i++) {
            int rr = rowBase + r0 + i;
            int bbn = rr >> 10, t = rr & (TT - 1);
            float4 o;
            o.x = (acc[i][0] + b4[0]) * LOG2EF; o.y = (acc[i][1] + b4[1]) * LOG2EF;
            o.z = (acc[i][2] + b4[2]) * LOG2EF; o.w = (acc[i][3] + b4[3]) * LOG2EF;
            *(float4*)&Vv2[(((size_t)(bbn * NH + h)) * TT + t) * HD + c0] = o;
        }
    } else {
        float beta = expf(lbeta[h]);
        float itemp = 1.0f / expf(ltemp[h]);
        // z==0: store Qf*ln2 ; z==1: store raw Kf
        float oscale = (z == 0) ? (LN2F / beta) : (1.0f / beta);
        float* __restrict__ dst = (z == 0) ? Qf2 : Kf;
#pragma unroll
        for (int i = 0; i < 4; i++) {
            int rr = rowBase + r0 + i;
            int bbn = rr >> 10, t = rr & (TT - 1);
            float v4[4];
#pragma unroll
            for (int j = 0; j < 4; j++) {
                float val = (acc[i][j] + b4[j]) * itemp;
                float zz = beta * val;
                v4[j] = (fmaxf(zz, 0.f) + log1pf(expf(-fabsf(zz)))) * oscale;
            }
            float4 o = { v4[0], v4[1], v4[2], v4[3] };
            *(float4*)&dst[(((size_t)(bbn * NH + h)) * TT + t) * HD + c0] = o;
        }
    }
}

// ---------------- Kernel 2: per-chunk local sums ----------------
// grid: (CH*2, NH, B)  block: 256. lane owns p = tid&63; qo = tid>>6 gives 8 q's.
__launch_bounds__(256)
__global__ void k_chunk_reduce(const float* __restrict__ Kf, const float* __restrict__ Vv2,
                               float* __restrict__ aA, float* __restrict__ aD,
                               float* __restrict__ aCM)
{
    const int c = blockIdx.x >> 1, qh = blockIdx.x & 1;
    const int bh = blockIdx.z * NH + blockIdx.y;
    const int tid = threadIdx.x;

    __shared__ __align__(16) float sK[CL * HD];
    __shared__ __align__(16) float sV2[CL * HD];
    __shared__ __align__(16) float sM02[CL * HD];

    size_t base = ((size_t)bh * TT + (size_t)c * CL) * HD;
    const float4* K4 = (const float4*)(Kf + base);
    const float4* V4 = (const float4*)(Vv2 + base);
#pragma unroll
    for (int r = 0; r < 2; r++) {
        int f = tid + 256 * r;
        float4 kv = K4[f];
        ((float4*)sK)[f] = kv;
        float4 m;
        m.x = flog2(kv.x + EPSF); m.y = flog2(kv.y + EPSF);
        m.z = flog2(kv.z + EPSF); m.w = flog2(kv.w + EPSF);
        ((float4*)sM02)[f] = m;
        ((float4*)sV2)[f] = V4[f];
    }
    __syncthreads();

    const int p = tid & 63, qo = tid >> 6;
    const int q0 = qh * 32 + qo * 8;
    float A[8] = {};
    float AD = 0.f, cmx = 0.f;
    const bool doD = (qh == 0) && (tid < 64);

    for (int s = 0; s < CL; s++) {
        float vp = sV2[s * HD + p];
        float mp = sM02[s * HD + p];
        float4 ka = *(const float4*)&sK[s * HD + q0];
        float4 kb = *(const float4*)&sK[s * HD + q0 + 4];
        A[0] += fexp2(fmaf(vp, ka.x, mp));
        A[1] += fexp2(fmaf(vp, ka.y, mp));
        A[2] += fexp2(fmaf(vp, ka.z, mp));
        A[3] += fexp2(fmaf(vp, ka.w, mp));
        A[4] += fexp2(fmaf(vp, kb.x, mp));
        A[5] += fexp2(fmaf(vp, kb.y, mp));
        A[6] += fexp2(fmaf(vp, kb.z, mp));
        A[7] += fexp2(fmaf(vp, kb.w, mp));
        if (doD) {
            float kn = sK[s * HD + tid];
            float mn = sM02[s * HD + tid];
            AD += fexp2(fmaf(kn, LOG2EF, mn));
            cmx = fmaxf(cmx, kn + EPSF);
        }
    }

    size_t abase = ((size_t)bh * CH + c) * 4096 + (size_t)p * HD + q0;
    float4 o0 = { A[0], A[1], A[2], A[3] };
    float4 o1 = { A[4], A[5], A[6], A[7] };
    *(float4*)&aA[abase] = o0;
    *(float4*)&aA[abase + 4] = o1;
    if (doD) {
        size_t dbase = ((size_t)bh * CH + c) * HD + tid;
        aD[dbase] = AD; aCM[dbase] = cmx;
    }
}

// ---------------- Kernel 3: exclusive scan of chunk aggregates (plain sums) ----
__global__ void k_scan_agg(float* __restrict__ aA, float* __restrict__ aD,
                           float* __restrict__ aCM, int BH)
{
    int idx = blockIdx.x * 256 + threadIdx.x;
    int nA = BH * 4096, nD = BH * 64;
    if (idx < nA) {
        int bh = idx >> 12, pn = idx & 4095;
        float Sr = 0.f;
        for (int c = 0; c < CH; c++) {
            size_t off = ((size_t)bh * CH + c) * 4096 + pn;
            float t = aA[off]; aA[off] = Sr; Sr += t;
        }
    } else if (idx < nA + nD) {
        int i = idx - nA; int bh = i >> 6, n = i & 63;
        float Sr = 0.f;
        for (int c = 0; c < CH; c++) {
            size_t off = ((size_t)bh * CH + c) * HD + n;
            float t = aD[off]; aD[off] = Sr; Sr += t;
        }
    } else if (idx < nA + 2 * nD) {
        int i = idx - nA - nD; int bh = i >> 6, n = i & 63;
        float r = 0.f;
        for (int c = 0; c < CH; c++) {
            size_t off = ((size_t)bh * CH + c) * HD + n;
            float v = aCM[off]; aCM[off] = r; r = fmaxf(r, v);
        }
    }
}

// ---------------- Kernel 4: denominator / c1 per t ----------------
// grid: (CH, NH, B), 64 threads (lane owns n). Stores c1[t], invden[t].
__launch_bounds__(64)
__global__ void k_den(const float* __restrict__ Kf, const float* __restrict__ Qf2,
                      const float* __restrict__ aD, const float* __restrict__ aCM,
                      float* __restrict__ c1f, float* __restrict__ invd)
{
    const int c = blockIdx.x;
    const int bh = blockIdx.z * NH + blockIdx.y;
    const int n = threadIdx.x;
    size_t dbase = ((size_t)bh * CH + c) * HD + n;
    float AD = aD[dbase], cmx = aCM[dbase];
    size_t base = ((size_t)bh * TT + (size_t)c * CL) * HD + n;
    float* outc = c1f + (size_t)bh * TT + c * CL;
    float* outi = invd + (size_t)bh * TT + c * CL;

    for (int s = 0; s < CL; s++) {
        float kn = Kf[base + (size_t)s * HD];
        float qn = Qf2[base + (size_t)s * HD];
        float mn = flog2(kn + EPSF);
        AD += fexp2(fmaf(kn, LOG2EF, mn));
        cmx = fmaxf(cmx, kn + EPSF);
        float t1 = qn * flog2(cmx);
        float t2 = qn * flog2(AD);
#pragma unroll
        for (int off = 1; off <= 32; off <<= 1) {
            t1 += __shfl_xor(t1, off);
            t2 += __shfl_xor(t2, off);
        }
        if (n == 0) {
            outc[s] = t1;
            outi[s] = 1.0f / (t2 - t1 + EPSF);
        }
    }
}

// ---------------- Kernel 5: within-chunk rescan + output Y ----------------
// grid: (CH, NH, B), 256 threads (4 waves). Thread owns 2 q's (qA, qA+32) x 8 p's.
__launch_bounds__(256)
__global__ void k_chunk_out(const float* __restrict__ Kf, const float* __restrict__ Vv2,
                            const float* __restrict__ Qf2, const float* __restrict__ aA,
                            const float* __restrict__ c1f, const float* __restrict__ invd,
                            const float* __restrict__ lsharp, float* __restrict__ Ym)
{
    const int c = blockIdx.x, hh = blockIdx.y, bb = blockIdx.z;
    const int bh = bb * NH + hh;
    const int tid = threadIdx.x;

    __shared__ __align__(16) float sK[CL * HD];
    __shared__ __align__(16) float sV2[CL * HD];
    __shared__ __align__(16) float sM02[CL * HD];
    __shared__ __align__(16) float sQ2[CL * HD];

    size_t base = ((size_t)bh * TT + (size_t)c * CL) * HD;
    const float4* K4 = (const float4*)(Kf + base);
    const float4* V4 = (const float4*)(Vv2 + base);
    const float4* Q4 = (const float4*)(Qf2 + base);
#pragma unroll
    for (int r = 0; r < 2; r++) {
        int f = tid + 256 * r;
        float4 kv = K4[f];
        ((float4*)sK)[f] = kv;
        float4 m;
        m.x = flog2(kv.x + EPSF); m.y = flog2(kv.y + EPSF);
        m.z = flog2(kv.z + EPSF); m.w = flog2(kv.w + EPSF);
        ((float4*)sM02)[f] = m;
        ((float4*)sV2)[f] = V4[f];
        ((float4*)sQ2)[f] = Q4[f];
    }
    __syncthreads();

    const int lane = tid & 63, w = tid >> 6;
    const int g = lane >> 3, qil = lane & 7;
    const int qA = w * 8 + qil, qB = qA + 32;
    const int p0 = g * 8;

    float A[8], Bq[8];
    size_t abase = ((size_t)bh * CH + c) * 4096;
#pragma unroll
    for (int j = 0; j < 8; j++) {
        A[j]  = aA[abase + (size_t)(p0 + j) * HD + qA];
        Bq[j] = aA[abase + (size_t)(p0 + j) * HD + qB];
    }
    const float sharp = expf(lsharp[hh]);
    const float invT = 1.0f / (float)TT;
    const float* c1p = c1f + (size_t)bh * TT + c * CL;
    const float* ivp = invd + (size_t)bh * TT + c * CL;

    for (int s = 0; s < CL; s++) {
        float kqA = sK[s * HD + qA];
        float kqB = sK[s * HD + qB];
        float partA = 0.f, partB = 0.f;
#pragma unroll
        for (int j4 = 0; j4 < 2; j4++) {
            float4 vv = *(const float4*)&sV2[s * HD + p0 + j4 * 4];
            float4 mm = *(const float4*)&sM02[s * HD + p0 + j4 * 4];
            float4 qv = *(const float4*)&sQ2[s * HD + p0 + j4 * 4];
#define STEP(comp, jj) { \
            A[jj]  += fexp2(fmaf(vv.comp, kqA, mm.comp)); \
            partA = fmaf(qv.comp, flog2(A[jj]), partA); \
            Bq[jj] += fexp2(fmaf(vv.comp, kqB, mm.comp)); \
            partB = fmaf(qv.comp, flog2(Bq[jj]), partB); }
            STEP(x, j4 * 4 + 0)
            STEP(y, j4 * 4 + 1)
            STEP(z, j4 * 4 + 2)
            STEP(w, j4 * 4 + 3)
#undef STEP
        }
        partA += __shfl_xor(partA, 8);
        partA += __shfl_xor(partA, 16);
        partA += __shfl_xor(partA, 32);
        partB += __shfl_xor(partB, 8);
        partB += __shfl_xor(partB, 16);
        partB += __shfl_xor(partB, 32);

        float c1v = c1p[s], iv = ivp[s];
        int tg = c * CL + s;
        float scale = (float)(tg + 1) * invT;
        float yA = (partA - c1v) * iv;
        float yB = (partB - c1v) * iv;
        float oA = copysignf(fexp2(sharp * flog2(fabsf(yA))), yA) * scale;
        float oB = copysignf(fexp2(sharp * flog2(fabsf(yB))), yB) * scale;
        if (g == 0) {
            float* yrow = Ym + ((size_t)(bb * TT + tg)) * DIM + hh * HD;
            yrow[qA] = oA;
            yrow[qB] = oB;
        }
    }
}

// ---------------- Kernel 6: output projection ----------------
__launch_bounds__(256)
__global__ void k_gemm_out(const float* __restrict__ A, const float* __restrict__ w,
                           const float* __restrict__ bias, float* __restrict__ out)
{
    const int rowBase = blockIdx.y * 64;
    const int colBase = blockIdx.x * 64;
    __shared__ __align__(16) float As[16][68];
    __shared__ __align__(16) float Bs[16][64];
    const int tid = threadIdx.x;
    const int ty = tid >> 4, tx = tid & 15;
    const int r0 = ty * 4, c0 = tx * 4;
    const int ar = tid >> 2, ak = (tid & 3) * 4;
    const int bkr = tid >> 4, bc = (tid & 15) * 4;

    float acc[4][4] = {};
    for (int k0 = 0; k0 < DIM; k0 += 16) {
        float4 av = *(const float4*)&A[(size_t)(rowBase + ar) * DIM + k0 + ak];
        As[ak + 0][ar] = av.x; As[ak + 1][ar] = av.y;
        As[ak + 2][ar] = av.z; As[ak + 3][ar] = av.w;
        *(float4*)&Bs[bkr][bc] = *(const float4*)&w[(size_t)(k0 + bkr) * DIM + colBase + bc];
        __syncthreads();
#pragma unroll
        for (int kk = 0; kk < 16; kk++) {
            float4 a = *(const float4*)&As[kk][r0];
            float4 b = *(const float4*)&Bs[kk][c0];
            float aa[4] = {a.x, a.y, a.z, a.w};
            float bb[4] = {b.x, b.y, b.z, b.w};
#pragma unroll
            for (int i = 0; i < 4; i++)
#pragma unroll
                for (int j = 0; j < 4; j++)
                    acc[i][j] = fmaf(aa[i], bb[j], acc[i][j]);
        }
        __syncthreads();
    }
    float b4[4] = { bias[colBase + c0 + 0], bias[colBase + c0 + 1],
                    bias[colBase + c0 + 2], bias[colBase + c0 + 3] };
#pragma unroll
    for (int i = 0; i < 4; i++) {
        int rr = rowBase + r0 + i;
        float4 o;
        o.x = acc[i][0] + b4[0]; o.y = acc[i][1] + b4[1];
        o.z = acc[i][2] + b4[2]; o.w = acc[i][3] + b4[3];
        *(float4*)&out[(size_t)rr * DIM + colBase + c0] = o;
    }
}

extern "C" void kernel_launch(void* const* d_in, const int* in_sizes, int n_in,
                              void* d_out, int out_size, void* d_ws, size_t ws_size,
                              hipStream_t stream)
{
    const float* x  = (const float*)d_in[0];
    const float* wq = (const float*)d_in[1];
    const float* bq = (const float*)d_in[2];
    const float* wk = (const float*)d_in[3];
    const float* bk = (const float*)d_in[4];
    const float* wv = (const float*)d_in[5];
    const float* bv = (const float*)d_in[6];
    const float* wo = (const float*)d_in[7];
    const float* bo = (const float*)d_in[8];
    const float* lb = (const float*)d_in[9];
    const float* lt = (const float*)d_in[10];
    const float* ls = (const float*)d_in[11];

    const int B  = in_sizes[0] / (TT * DIM);   // 2
    const int BH = B * NH;                     // 16

    float* ws   = (float*)d_ws;
    float* Qf2  = ws;
    float* Kf   = Qf2 + (size_t)BH * TT * HD;
    float* Vv2  = Kf  + (size_t)BH * TT * HD;
    float* Ym   = Vv2 + (size_t)BH * TT * HD;
    float* aA   = Ym  + (size_t)B * TT * DIM;
    float* aD   = aA  + (size_t)BH * CH * 4096;
    float* aCM  = aD  + (size_t)BH * CH * HD;
    float* c1f  = aCM + (size_t)BH * CH * HD;
    float* invd = c1f + (size_t)BH * TT;

    dim3 g1(NH, (B * TT) / 64, 3);
    k_gemm_qkv<<<g1, 256, 0, stream>>>(x, wq, bq, wk, bk, wv, bv, lb, lt, Qf2, Kf, Vv2);

    dim3 g2(CH * 2, NH, B);
    k_chunk_reduce<<<g2, 256, 0, stream>>>(Kf, Vv2, aA, aD, aCM);

    int ntot = BH * 4096 + 2 * BH * 64;
    k_scan_agg<<<(ntot + 255) / 256, 256, 0, stream>>>(aA, aD, aCM, BH);

    dim3 g4(CH, NH, B);
    k_den<<<g4, 64, 0, stream>>>(Kf, Qf2, aD, aCM, c1f, invd);

    k_chunk_out<<<g4, 256, 0, stream>>>(Kf, Vv2, Qf2, aA, c1f, invd, ls, Ym);

    dim3 g6(NH, (B * TT) / 64, 1);
    k_gemm_out<<<g6, 256, 0, stream>>>(Ym, wo, bo, (float*)d_out);
}